// Round 4
// baseline (913.172 us; speedup 1.0000x reference)
//
#include <hip/hip_runtime.h>
#include <hip/hip_bf16.h>
#include <stdint.h>

typedef __bf16 bf16;
typedef __bf16 bf16x8 __attribute__((ext_vector_type(8)));
typedef float f32x4 __attribute__((ext_vector_type(4)));

#define T_SEQ 2048
#define NH 32
#define NKV 8
#define HD 128
#define HDIM 4096
#define QKV_OUT 6144

__device__ __forceinline__ void g2l16(const void* g, void* l) {
  __builtin_amdgcn_global_load_lds(
      (const __attribute__((address_space(1))) void*)g,
      (__attribute__((address_space(3))) void*)l, 16, 0, 0);
}

// ---------------- f32 -> bf16 convert ----------------
__global__ __launch_bounds__(256) void cvt_kernel(const float* __restrict__ in,
                                                  bf16* __restrict__ out, int n) {
  int stride = gridDim.x * blockDim.x * 8;
  for (int i = (blockIdx.x * blockDim.x + threadIdx.x) * 8; i < n; i += stride) {
    float4 a = *(const float4*)(in + i);
    float4 b = *(const float4*)(in + i + 4);
    bf16x8 o;
    o[0] = (bf16)a.x; o[1] = (bf16)a.y; o[2] = (bf16)a.z; o[3] = (bf16)a.w;
    o[4] = (bf16)b.x; o[5] = (bf16)b.y; o[6] = (bf16)b.z; o[7] = (bf16)b.w;
    *(bf16x8*)(out + i) = o;
  }
}

__global__ __launch_bounds__(256) void zero_f32(float* __restrict__ p, int n) {
  int i = blockIdx.x * 256 + threadIdx.x;
  if (i < n) p[i] = 0.f;
}

// ---------------- 128x128 bf16 MFMA GEMM (m97 structure): C = A @ B^T ----------------
// A[M][K], B[N][K] row-major bf16, C[M][N] f32. M,N mult of 128, K mult of 32.
__global__ __launch_bounds__(256)
void gemm128(const bf16* __restrict__ A, const bf16* __restrict__ B,
             float* __restrict__ C, int M, int N, int K) {
  __shared__ bf16 As[128 * 32];
  __shared__ bf16 Bs[128 * 32];
  const int tid = threadIdx.x;
  const int wid = tid >> 6, lane = tid & 63;
  const int bm = blockIdx.x * 128, bn = blockIdx.y * 128;
  const int wr = (wid >> 1) * 64, wc = (wid & 1) * 64;
  const int lr = lane & 15, lk = (lane >> 4) * 8;
  const int srow = wid * 32 + (lane >> 2);
  const int scol = (lane & 3) * 8;
  const bf16* Ag = A + (size_t)(bm + srow) * K + scol;
  const bf16* Bg = B + (size_t)(bn + srow) * K + scol;
  bf16* Al = As + wid * 1024;  // wave region: rows [wid*32, wid*32+32)
  bf16* Bl = Bs + wid * 1024;
  f32x4 acc[4][4] = {};
  for (int k0 = 0; k0 < K; k0 += 32) {
    g2l16(Ag + k0, Al);
    g2l16(Ag + k0 + (size_t)16 * K, Al + 512);
    g2l16(Bg + k0, Bl);
    g2l16(Bg + k0 + (size_t)16 * K, Bl + 512);
    __syncthreads();
    bf16x8 af[4], bfv[4];
#pragma unroll
    for (int m = 0; m < 4; ++m)
      af[m] = *(const bf16x8*)(As + (wr + m * 16 + lr) * 32 + lk);
#pragma unroll
    for (int n = 0; n < 4; ++n)
      bfv[n] = *(const bf16x8*)(Bs + (wc + n * 16 + lr) * 32 + lk);
#pragma unroll
    for (int m = 0; m < 4; ++m)
#pragma unroll
      for (int n = 0; n < 4; ++n)
        acc[m][n] = __builtin_amdgcn_mfma_f32_16x16x32_bf16(af[m], bfv[n], acc[m][n], 0, 0, 0);
    __syncthreads();
  }
  const int orow = (lane >> 4) * 4;
#pragma unroll
  for (int m = 0; m < 4; ++m)
#pragma unroll
    for (int n = 0; n < 4; ++n)
#pragma unroll
      for (int j = 0; j < 4; ++j)
        C[(size_t)(bm + wr + m * 16 + orow + j) * N + (bn + wc + n * 16 + lr)] = acc[m][n][j];
}

// ---------------- 64x64 LoRA GEMM ----------------
// MODE 0: store bf16 to outb; MODE 1: atomicAdd outf[cidx[r]*ldc+c] += v*alpha;
// MODE 2: split-K (gridDim.z chunks), atomicAdd outf[r*ldc+c] += v.
template <int GATHER_A, int MODE>
__global__ __launch_bounds__(256)
void gemm64(const bf16* __restrict__ A, const bf16* __restrict__ B,
            const int* __restrict__ aidx, const int* __restrict__ cidx,
            bf16* __restrict__ outb, float* __restrict__ outf,
            int M, int N, int K, int ldc, float alpha) {
  __shared__ bf16 As[64 * 32];
  __shared__ bf16 Bs[64 * 32];
  const int tid = threadIdx.x;
  const int wid = tid >> 6, lane = tid & 63;
  const int bm = blockIdx.x * 64, bn = blockIdx.y * 64;
  const int wr = (wid >> 1) * 32, wc = (wid & 1) * 32;
  const int lr = lane & 15, lk = (lane >> 4) * 8;
  int arow = bm + wid * 16 + (lane >> 2);
  if (GATHER_A) arow = aidx[arow];
  const int scol = (lane & 3) * 8;
  const bf16* Ag = A + (size_t)arow * K + scol;
  const bf16* Bg = B + (size_t)(bn + wid * 16 + (lane >> 2)) * K + scol;
  bf16* Al = As + wid * 512;
  bf16* Bl = Bs + wid * 512;
  int kbeg = 0, kend = K;
  if (MODE == 2) { int kc = K / gridDim.z; kbeg = blockIdx.z * kc; kend = kbeg + kc; }
  f32x4 acc[2][2] = {};
  for (int k0 = kbeg; k0 < kend; k0 += 32) {
    g2l16(Ag + k0, Al);
    g2l16(Bg + k0, Bl);
    __syncthreads();
    bf16x8 af[2], bfv[2];
#pragma unroll
    for (int m = 0; m < 2; ++m)
      af[m] = *(const bf16x8*)(As + (wr + m * 16 + lr) * 32 + lk);
#pragma unroll
    for (int n = 0; n < 2; ++n)
      bfv[n] = *(const bf16x8*)(Bs + (wc + n * 16 + lr) * 32 + lk);
#pragma unroll
    for (int m = 0; m < 2; ++m)
#pragma unroll
      for (int n = 0; n < 2; ++n)
        acc[m][n] = __builtin_amdgcn_mfma_f32_16x16x32_bf16(af[m], bfv[n], acc[m][n], 0, 0, 0);
    __syncthreads();
  }
  const int orow = (lane >> 4) * 4;
#pragma unroll
  for (int m = 0; m < 2; ++m)
#pragma unroll
    for (int n = 0; n < 2; ++n)
#pragma unroll
      for (int j = 0; j < 4; ++j) {
        int r = bm + wr + m * 16 + orow + j;
        int c = bn + wc + n * 16 + lr;
        float v = acc[m][n][j];
        if (MODE == 0)      outb[(size_t)r * ldc + c] = (bf16)(v * alpha);
        else if (MODE == 1) atomicAdd(outf + (size_t)cidx[r] * ldc + c, v * alpha);
        else                atomicAdd(outf + (size_t)r * ldc + c, v);
      }
}

// ---------------- RoPE on Q (fold softmax scale * log2e), write bf16 [t][h][d] ----------------
__global__ __launch_bounds__(256)
void rope_q(const float* __restrict__ qkv, const float* __restrict__ cosp,
            const float* __restrict__ sinp, bf16* __restrict__ qb) {
  int idx = blockIdx.x * 4 + (threadIdx.x >> 6);  // t*32 + h
  int d = threadIdx.x & 63;
  int t = idx >> 5, h = idx & 31;
  const float* src = qkv + (size_t)t * QKV_OUT + (h >> 2) * 768 + (h & 3) * 128;
  float x0 = src[d], x1 = src[d + 64];
  float c0 = cosp[t * HD + d], c1 = cosp[t * HD + d + 64];
  float s0 = sinp[t * HD + d], s1 = sinp[t * HD + d + 64];
  const float SC = 0.08838834764831845f * 1.4426950408889634f;  // 1/sqrt(128) * log2(e)
  bf16* dst = qb + ((size_t)t * NH + h) * HD;
  dst[d]      = (bf16)((x0 * c0 - x1 * s0) * SC);
  dst[d + 64] = (bf16)((x1 * c1 + x0 * s1) * SC);
}

// ---------------- RoPE on K, write bf16 [t][kvh][d] ----------------
__global__ __launch_bounds__(256)
void rope_k(const float* __restrict__ qkv, const float* __restrict__ cosp,
            const float* __restrict__ sinp, bf16* __restrict__ kb) {
  int idx = blockIdx.x * 4 + (threadIdx.x >> 6);  // t*8 + kvh
  int d = threadIdx.x & 63;
  int t = idx >> 3, kvh = idx & 7;
  const float* src = qkv + (size_t)t * QKV_OUT + kvh * 768 + 512;
  float x0 = src[d], x1 = src[d + 64];
  float c0 = cosp[t * HD + d], c1 = cosp[t * HD + d + 64];
  float s0 = sinp[t * HD + d], s1 = sinp[t * HD + d + 64];
  bf16* dst = kb + ((size_t)t * NKV + kvh) * HD;
  dst[d]      = (bf16)(x0 * c0 - x1 * s0);
  dst[d + 64] = (bf16)(x1 * c1 + x0 * s1);
}

// ---------------- V transpose: qkv slot5 -> vtb[kvh][d][t] bf16 ----------------
__global__ __launch_bounds__(256)
void v_trans(const float* __restrict__ qkv, bf16* __restrict__ vtb) {
  __shared__ bf16 tile[128][72];
  const int kvh = blockIdx.y;
  const int t0 = blockIdx.x * 64;
  const int tid = threadIdx.x;
  for (int i = tid; i < 64 * 32; i += 256) {
    int t = i >> 5;
    int dq = (i & 31) * 4;
    const float* p = qkv + (size_t)(t0 + t) * QKV_OUT + kvh * 768 + 640 + dq;
    float4 v = *(const float4*)p;
    tile[dq + 0][t] = (bf16)v.x;
    tile[dq + 1][t] = (bf16)v.y;
    tile[dq + 2][t] = (bf16)v.z;
    tile[dq + 3][t] = (bf16)v.w;
  }
  __syncthreads();
  for (int i = tid; i < 128 * 8; i += 256) {
    int d = i >> 3;
    int tt = (i & 7) * 8;
    bf16x8 v;
#pragma unroll
    for (int j = 0; j < 8; ++j) v[j] = tile[d][tt + j];
    *(bf16x8*)(vtb + ((size_t)kvh * HD + d) * T_SEQ + t0 + tt) = v;
  }
}

// ---------------- cache copy + beacon-rope fill ----------------
__global__ __launch_bounds__(256)
void cache_copy(const float* __restrict__ kc, const float* __restrict__ vc,
                float* __restrict__ kout, float* __restrict__ vout) {
  int i = blockIdx.x * 256 + threadIdx.x;
  kout[i] = kc[i];
  vout[i] = vc[i];
}

__global__ __launch_bounds__(256)
void cache_fill(const float* __restrict__ qkv, const int* __restrict__ mem_idx,
                const int* __restrict__ blk_off, const float* __restrict__ bcos,
                const float* __restrict__ bsin,
                float* __restrict__ kout, float* __restrict__ vout) {
  const int m = blockIdx.x;
  const int row = mem_idx[m];
  const int blk = blk_off[m >> 6];
  const int off = m & 63;
  const int tid = threadIdx.x;
  for (int i = tid; i < NKV * 64; i += 256) {
    int kvh = i >> 6, d = i & 63;
    const float* ks = qkv + (size_t)row * QKV_OUT + kvh * 768 + 512;  // pre-rope k
    const float* vs = ks + 128;
    float x0 = ks[d], x1 = ks[d + 64];
    float c0 = bcos[m * HD + d], c1 = bcos[m * HD + d + 64];
    float s0 = bsin[m * HD + d], s1 = bsin[m * HD + d + 64];
    size_t base = (((size_t)blk * 64 + off) * NKV + kvh) * HD;
    kout[base + d]      = x0 * c0 - x1 * s0;
    kout[base + d + 64] = x1 * c1 + x0 * s1;
    vout[base + d]      = vs[d];
    vout[base + d + 64] = vs[d + 64];
  }
}

// ---------------- causal flash attention, bf16 MFMA ----------------
// grid (32 qtiles of 64, 32 heads), 4 waves x 16 q-rows. KV tiles of 32.
__global__ __launch_bounds__(256)
void flash(const bf16* __restrict__ qb, const bf16* __restrict__ kb,
           const bf16* __restrict__ vtb, bf16* __restrict__ attnb) {
  __shared__ bf16 Ks[32 * 128];   // [kv][d] (XOR-swizzled)
  __shared__ bf16 Vs[128 * 32];   // [d][kv] (XOR-swizzled)
  __shared__ bf16 Ps[4][16 * 32]; // per-wave P
  const int q0 = blockIdx.x * 64;
  const int h = blockIdx.y;
  const int kvh = h >> 2;
  const int tid = threadIdx.x;
  const int wid = tid >> 6, lane = tid & 63;
  const int lr = lane & 15, lg = lane >> 4;
  const int lk = lg * 8;
  bf16x8 qf[4];
  {
    const bf16* qsrc = qb + (((size_t)(q0 + wid * 16 + lr)) * NH + h) * HD + lk;
#pragma unroll
    for (int kk = 0; kk < 4; ++kk) qf[kk] = *(const bf16x8*)(qsrc + kk * 32);
  }
  f32x4 o[8] = {};
  float mrow[4] = {-1e30f, -1e30f, -1e30f, -1e30f};
  float lrow[4] = {0.f, 0.f, 0.f, 0.f};
  const int kv_end = q0 + 64;
  const int krr = wid * 8 + lg;          // K staging row (issue0), +4 for issue1
  const int kcb = lr * 16;               // byte within 256B K row
  const int vdr = wid * 32 + (lane >> 2); // V staging row (issue0), +16 for issue1
  const int vcb = (lane & 3) * 16;       // byte within 64B V row
  for (int jt = 0; jt < kv_end; jt += 32) {
    {
      int d0 = (kcb ^ ((krr & 7) << 4)) >> 1;
      g2l16(kb + ((size_t)(jt + krr) * NKV + kvh) * HD + d0, Ks + wid * 1024);
      int rr1 = krr + 4;
      int d1 = (kcb ^ ((rr1 & 7) << 4)) >> 1;
      g2l16(kb + ((size_t)(jt + rr1) * NKV + kvh) * HD + d1, Ks + wid * 1024 + 512);
      int t0 = (vcb ^ (((vdr >> 1) & 3) << 4)) >> 1;
      g2l16(vtb + ((size_t)kvh * HD + vdr) * T_SEQ + jt + t0, Vs + wid * 1024);
      int vdr1 = vdr + 16;
      int t1 = (vcb ^ (((vdr1 >> 1) & 3) << 4)) >> 1;
      g2l16(vtb + ((size_t)kvh * HD + vdr1) * T_SEQ + jt + t1, Vs + wid * 1024 + 512);
    }
    __syncthreads();
    f32x4 S[2] = {};
    const char* KsB = (const char*)Ks;
#pragma unroll
    for (int ch = 0; ch < 2; ++ch) {
      int row = ch * 16 + lr;
      int rbase = row * 256;
      int swz = (row & 7) << 4;
#pragma unroll
      for (int kk = 0; kk < 4; ++kk) {
        bf16x8 kf = *(const bf16x8*)(KsB + rbase + ((kk * 64 + lg * 16) ^ swz));
        S[ch] = __builtin_amdgcn_mfma_f32_16x16x32_bf16(qf[kk], kf, S[ch], 0, 0, 0);
      }
    }
    const int baserow = q0 + wid * 16 + lg * 4;
    float corr[4];
#pragma unroll
    for (int j = 0; j < 4; ++j) {
      int row = baserow + j;
      float s0 = (jt + lr <= row)      ? S[0][j] : -1e30f;
      float s1 = (jt + 16 + lr <= row) ? S[1][j] : -1e30f;
      float tmx = fmaxf(s0, s1);
#pragma unroll
      for (int off = 1; off < 16; off <<= 1)
        tmx = fmaxf(tmx, __shfl_xor(tmx, off, 64));
      float mn = fmaxf(mrow[j], tmx);
      corr[j] = exp2f(mrow[j] - mn);
      mrow[j] = mn;
      float p0 = (s0 <= -1e29f) ? 0.f : exp2f(s0 - mn);
      float p1 = (s1 <= -1e29f) ? 0.f : exp2f(s1 - mn);
      S[0][j] = p0; S[1][j] = p1;
      float ps = p0 + p1;
#pragma unroll
      for (int off = 1; off < 16; off <<= 1)
        ps += __shfl_xor(ps, off, 64);
      lrow[j] = lrow[j] * corr[j] + ps;
    }
#pragma unroll
    for (int db = 0; db < 8; ++db) {
      o[db][0] *= corr[0]; o[db][1] *= corr[1];
      o[db][2] *= corr[2]; o[db][3] *= corr[3];
    }
    bf16* pw = Ps[wid];
#pragma unroll
    for (int j = 0; j < 4; ++j) {
      pw[(lg * 4 + j) * 32 + lr]      = (bf16)S[0][j];
      pw[(lg * 4 + j) * 32 + 16 + lr] = (bf16)S[1][j];
    }
    asm volatile("s_waitcnt lgkmcnt(0)" ::: "memory");
    bf16x8 pa = *(const bf16x8*)(pw + lr * 32 + lk);
    const char* VsB = (const char*)Vs;
    int vswz = ((lr >> 1) & 3) << 4;
#pragma unroll
    for (int db = 0; db < 8; ++db) {
      bf16x8 vf = *(const bf16x8*)(VsB + (db * 16 + lr) * 64 + ((lg * 16) ^ vswz));
      o[db] = __builtin_amdgcn_mfma_f32_16x16x32_bf16(pa, vf, o[db], 0, 0, 0);
    }
    __syncthreads();
  }
#pragma unroll
  for (int j = 0; j < 4; ++j) {
    float inv = 1.f / lrow[j];
    bf16* od = attnb + (((size_t)(q0 + wid * 16 + lg * 4 + j)) * NH + h) * HD;
#pragma unroll
    for (int db = 0; db < 8; ++db)
      od[db * 16 + lr] = (bf16)(o[db][j] * inv);
  }
}

// ---------------- launcher ----------------
extern "C" void kernel_launch(void* const* d_in, const int* in_sizes, int n_in,
                              void* d_out, int out_size, void* d_ws, size_t ws_size,
                              hipStream_t stream) {
  (void)in_sizes; (void)n_in; (void)out_size; (void)ws_size;
  const float* hidden  = (const float*)d_in[0];
  const float* cosp    = (const float*)d_in[1];
  const float* sinp    = (const float*)d_in[2];
  const float* bcos    = (const float*)d_in[3];
  const float* bsin    = (const float*)d_in[4];
  const int*   mem_idx = (const int*)d_in[5];
  const int*   im_idx  = (const int*)d_in[6];
  const float* kc_in   = (const float*)d_in[7];
  const float* vc_in   = (const float*)d_in[8];
  const int*   blk_off = (const int*)d_in[9];
  const float* wqkv_w  = (const float*)d_in[10];
  const float* wqkv_A  = (const float*)d_in[11];
  const float* wqkv_B  = (const float*)d_in[12];
  const float* wqkv_MA = (const float*)d_in[13];
  const float* wqkv_MB = (const float*)d_in[14];
  const float* wo_w    = (const float*)d_in[15];
  const float* wo_A    = (const float*)d_in[16];
  const float* wo_B    = (const float*)d_in[17];
  const float* wo_MA   = (const float*)d_in[18];
  const float* wo_MB   = (const float*)d_in[19];

  char* ws = (char*)d_ws;
  size_t off = 0;
  auto alloc = [&](size_t b) { char* p = ws + off; off += (b + 255) & ~(size_t)255; return p; };
  bf16* xb    = (bf16*)alloc(2048ull * 4096 * 2);
  bf16* wqkvb = (bf16*)alloc(6144ull * 4096 * 2);
  bf16* wob   = (bf16*)alloc(4096ull * 4096 * 2);
  bf16* qAb   = (bf16*)alloc(256ull * 4096 * 2);
  bf16* qBb   = (bf16*)alloc(6144ull * 256 * 2);
  bf16* qMAb  = (bf16*)alloc(256ull * 4096 * 2);
  bf16* qMBb  = (bf16*)alloc(6144ull * 256 * 2);
  bf16* oAb   = (bf16*)alloc(256ull * 4096 * 2);
  bf16* oBb   = (bf16*)alloc(4096ull * 256 * 2);
  bf16* oMAb  = (bf16*)alloc(256ull * 4096 * 2);
  bf16* oMBb  = (bf16*)alloc(4096ull * 256 * 2);
  float* qkv  = (float*)alloc(2048ull * 6144 * 4);
  bf16* qb    = (bf16*)alloc(2048ull * 32 * 128 * 2);
  bf16* kbuf  = (bf16*)alloc(2048ull * 8 * 128 * 2);
  bf16* vtb   = (bf16*)alloc(8ull * 128 * 2048 * 2);
  bf16* attnb = (bf16*)alloc(2048ull * 4096 * 2);
  float* tf   = (float*)alloc(1280ull * 256 * 4);  // t_im|t_mem|t2_im|t2_mem (f32)
  bf16* tb    = (bf16*)alloc(1280ull * 256 * 2);
  float* t_im_f  = tf;               float* t_mem_f  = tf + 512 * 256;
  float* t2_im_f = tf + 640 * 256;   float* t2_mem_f = tf + 1152 * 256;
  bf16* t_im_b   = tb;               bf16* t_mem_b   = tb + 512 * 256;
  bf16* t2_im_b  = tb + 640 * 256;   bf16* t2_mem_b  = tb + 1152 * 256;
  (void)t_mem_f; (void)t2_mem_f;

  float* outp   = (float*)d_out;
  float* kc_out = outp + 2048ull * 4096;
  float* vc_out = kc_out + 4ull * 64 * 8 * 128;

  auto cvt = [&](const float* src, bf16* dst, size_t n) {
    size_t g = (n / 8 + 255) / 256;
    if (g > 2048) g = 2048;
    cvt_kernel<<<(unsigned)g, 256, 0, stream>>>(src, dst, (int)n);
  };
  cvt(hidden, xb, 2048ull * 4096);
  cvt(wqkv_w, wqkvb, 6144ull * 4096);
  cvt(wo_w, wob, 4096ull * 4096);
  cvt(wqkv_A, qAb, 256ull * 4096);
  cvt(wqkv_B, qBb, 6144ull * 256);
  cvt(wqkv_MA, qMAb, 256ull * 4096);
  cvt(wqkv_MB, qMBb, 6144ull * 256);
  cvt(wo_A, oAb, 256ull * 4096);
  cvt(wo_B, oBb, 4096ull * 256);
  cvt(wo_MA, oMAb, 256ull * 4096);
  cvt(wo_MB, oMBb, 4096ull * 256);
  zero_f32<<<1280, 256, 0, stream>>>(tf, 1280 * 256);

  // qkv = x @ wqkv^T (+ LoRA scatter-adds)
  gemm128<<<dim3(16, 48), 256, 0, stream>>>(xb, wqkvb, qkv, 2048, 6144, 4096);
  gemm64<1, 2><<<dim3(8, 4, 8), 256, 0, stream>>>(xb, qAb, im_idx, nullptr, nullptr, t_im_f, 512, 256, 4096, 256, 1.f);
  gemm64<1, 2><<<dim3(2, 4, 8), 256, 0, stream>>>(xb, qMAb, mem_idx, nullptr, nullptr, t_mem_f, 128, 256, 4096, 256, 1.f);
  cvt(tf, tb, 640 * 256);
  gemm64<0, 1><<<dim3(8, 96), 256, 0, stream>>>(t_im_b, qBb, nullptr, im_idx, nullptr, qkv, 512, 6144, 256, 6144, 1.f);
  gemm64<0, 1><<<dim3(2, 96), 256, 0, stream>>>(t_mem_b, qMBb, nullptr, mem_idx, nullptr, qkv, 128, 6144, 256, 6144, 1.f);

  // rope / extract / cache
  rope_q<<<16384, 256, 0, stream>>>(qkv, cosp, sinp, qb);
  rope_k<<<4096, 256, 0, stream>>>(qkv, cosp, sinp, kbuf);
  v_trans<<<dim3(32, 8), 256, 0, stream>>>(qkv, vtb);
  cache_copy<<<1024, 256, 0, stream>>>(kc_in, vc_in, kc_out, vc_out);
  cache_fill<<<128, 256, 0, stream>>>(qkv, mem_idx, blk_off, bcos, bsin, kc_out, vc_out);

  // attention
  flash<<<dim3(32, 32), 256, 0, stream>>>(qb, kbuf, vtb, attnb);

  // out = attn @ wo^T (+ LoRA scatter-adds)
  gemm128<<<dim3(16, 32), 256, 0, stream>>>(attnb, wob, outp, 2048, 4096, 4096);
  gemm64<1, 2><<<dim3(8, 4, 8), 256, 0, stream>>>(attnb, oAb, im_idx, nullptr, nullptr, t2_im_f, 512, 256, 4096, 256, 1.f);
  gemm64<1, 2><<<dim3(2, 4, 8), 256, 0, stream>>>(attnb, oMAb, mem_idx, nullptr, nullptr, t2_mem_f, 128, 256, 4096, 256, 1.f);
  cvt(t2_im_f, t2_im_b, 640 * 256);
  gemm64<0, 1><<<dim3(8, 64), 256, 0, stream>>>(t2_im_b, oBb, nullptr, im_idx, nullptr, outp, 512, 4096, 256, 4096, 1.f);
  gemm64<0, 1><<<dim3(2, 64), 256, 0, stream>>>(t2_mem_b, oMBb, nullptr, mem_idx, nullptr, outp, 128, 4096, 256, 4096, 1.f);
}

// Round 6
// 882.280 us; speedup vs baseline: 1.0350x; 1.0350x over previous
//
#include <hip/hip_runtime.h>
#include <hip/hip_bf16.h>
#include <stdint.h>

typedef __bf16 bf16;
typedef __bf16 bf16x8 __attribute__((ext_vector_type(8)));
typedef __bf16 bf16x4 __attribute__((ext_vector_type(4)));
typedef float f32x4 __attribute__((ext_vector_type(4)));

#define T_SEQ 2048
#define NH 32
#define NKV 8
#define HD 128
#define HDIM 4096
#define QKV_OUT 6144

__device__ __forceinline__ void g2l16(const void* g, void* l) {
  __builtin_amdgcn_global_load_lds(
      (const __attribute__((address_space(1))) void*)g,
      (__attribute__((address_space(3))) void*)l, 16, 0, 0);
}

// ---------------- f32 -> bf16 convert ----------------
__global__ __launch_bounds__(256) void cvt_kernel(const float* __restrict__ in,
                                                  bf16* __restrict__ out, int n) {
  int stride = gridDim.x * blockDim.x * 8;
  for (int i = (blockIdx.x * blockDim.x + threadIdx.x) * 8; i < n; i += stride) {
    float4 a = *(const float4*)(in + i);
    float4 b = *(const float4*)(in + i + 4);
    bf16x8 o;
    o[0] = (bf16)a.x; o[1] = (bf16)a.y; o[2] = (bf16)a.z; o[3] = (bf16)a.w;
    o[4] = (bf16)b.x; o[5] = (bf16)b.y; o[6] = (bf16)b.z; o[7] = (bf16)b.w;
    *(bf16x8*)(out + i) = o;
  }
}

__global__ __launch_bounds__(256) void zero_f32(float* __restrict__ p, int n) {
  int i = blockIdx.x * 256 + threadIdx.x;
  if (i < n) p[i] = 0.f;
}

// ---------------- 128x128 bf16 MFMA GEMM (m97 structure): C = A @ B^T ----------------
__global__ __launch_bounds__(256)
void gemm128(const bf16* __restrict__ A, const bf16* __restrict__ B,
             float* __restrict__ C, int M, int N, int K) {
  __shared__ bf16 As[128 * 32];
  __shared__ bf16 Bs[128 * 32];
  const int tid = threadIdx.x;
  const int wid = tid >> 6, lane = tid & 63;
  const int bm = blockIdx.x * 128, bn = blockIdx.y * 128;
  const int wr = (wid >> 1) * 64, wc = (wid & 1) * 64;
  const int lr = lane & 15, lk = (lane >> 4) * 8;
  const int srow = wid * 32 + (lane >> 2);
  const int scol = (lane & 3) * 8;
  const bf16* Ag = A + (size_t)(bm + srow) * K + scol;
  const bf16* Bg = B + (size_t)(bn + srow) * K + scol;
  bf16* Al = As + wid * 1024;
  bf16* Bl = Bs + wid * 1024;
  f32x4 acc[4][4] = {};
  for (int k0 = 0; k0 < K; k0 += 32) {
    g2l16(Ag + k0, Al);
    g2l16(Ag + k0 + (size_t)16 * K, Al + 512);
    g2l16(Bg + k0, Bl);
    g2l16(Bg + k0 + (size_t)16 * K, Bl + 512);
    __syncthreads();
    bf16x8 af[4], bfv[4];
#pragma unroll
    for (int m = 0; m < 4; ++m)
      af[m] = *(const bf16x8*)(As + (wr + m * 16 + lr) * 32 + lk);
#pragma unroll
    for (int n = 0; n < 4; ++n)
      bfv[n] = *(const bf16x8*)(Bs + (wc + n * 16 + lr) * 32 + lk);
#pragma unroll
    for (int m = 0; m < 4; ++m)
#pragma unroll
      for (int n = 0; n < 4; ++n)
        acc[m][n] = __builtin_amdgcn_mfma_f32_16x16x32_bf16(af[m], bfv[n], acc[m][n], 0, 0, 0);
    __syncthreads();
  }
  const int orow = (lane >> 4) * 4;
#pragma unroll
  for (int m = 0; m < 4; ++m)
#pragma unroll
    for (int n = 0; n < 4; ++n)
#pragma unroll
      for (int j = 0; j < 4; ++j)
        C[(size_t)(bm + wr + m * 16 + orow + j) * N + (bn + wc + n * 16 + lr)] = acc[m][n][j];
}

// ---------------- 64x64 LoRA GEMM ----------------
template <int GATHER_A, int MODE>
__global__ __launch_bounds__(256)
void gemm64(const bf16* __restrict__ A, const bf16* __restrict__ B,
            const int* __restrict__ aidx, const int* __restrict__ cidx,
            bf16* __restrict__ outb, float* __restrict__ outf,
            int M, int N, int K, int ldc, float alpha) {
  __shared__ bf16 As[64 * 32];
  __shared__ bf16 Bs[64 * 32];
  const int tid = threadIdx.x;
  const int wid = tid >> 6, lane = tid & 63;
  const int bm = blockIdx.x * 64, bn = blockIdx.y * 64;
  const int wr = (wid >> 1) * 32, wc = (wid & 1) * 32;
  const int lr = lane & 15, lk = (lane >> 4) * 8;
  int arow = bm + wid * 16 + (lane >> 2);
  if (GATHER_A) arow = aidx[arow];
  const int scol = (lane & 3) * 8;
  const bf16* Ag = A + (size_t)arow * K + scol;
  const bf16* Bg = B + (size_t)(bn + wid * 16 + (lane >> 2)) * K + scol;
  bf16* Al = As + wid * 512;
  bf16* Bl = Bs + wid * 512;
  int kbeg = 0, kend = K;
  if (MODE == 2) { int kc = K / gridDim.z; kbeg = blockIdx.z * kc; kend = kbeg + kc; }
  f32x4 acc[2][2] = {};
  for (int k0 = kbeg; k0 < kend; k0 += 32) {
    g2l16(Ag + k0, Al);
    g2l16(Bg + k0, Bl);
    __syncthreads();
    bf16x8 af[2], bfv[2];
#pragma unroll
    for (int m = 0; m < 2; ++m)
      af[m] = *(const bf16x8*)(As + (wr + m * 16 + lr) * 32 + lk);
#pragma unroll
    for (int n = 0; n < 2; ++n)
      bfv[n] = *(const bf16x8*)(Bs + (wc + n * 16 + lr) * 32 + lk);
#pragma unroll
    for (int m = 0; m < 2; ++m)
#pragma unroll
      for (int n = 0; n < 2; ++n)
        acc[m][n] = __builtin_amdgcn_mfma_f32_16x16x32_bf16(af[m], bfv[n], acc[m][n], 0, 0, 0);
    __syncthreads();
  }
  const int orow = (lane >> 4) * 4;
#pragma unroll
  for (int m = 0; m < 2; ++m)
#pragma unroll
    for (int n = 0; n < 2; ++n)
#pragma unroll
      for (int j = 0; j < 4; ++j) {
        int r = bm + wr + m * 16 + orow + j;
        int c = bn + wc + n * 16 + lr;
        float v = acc[m][n][j];
        if (MODE == 0)      outb[(size_t)r * ldc + c] = (bf16)(v * alpha);
        else if (MODE == 1) atomicAdd(outf + (size_t)cidx[r] * ldc + c, v * alpha);
        else                atomicAdd(outf + (size_t)r * ldc + c, v);
      }
}

// ---------------- RoPE on Q (fold softmax scale * log2e), write bf16 [t][h][d] ----------------
__global__ __launch_bounds__(256)
void rope_q(const float* __restrict__ qkv, const float* __restrict__ cosp,
            const float* __restrict__ sinp, bf16* __restrict__ qb) {
  int idx = blockIdx.x * 4 + (threadIdx.x >> 6);
  int d = threadIdx.x & 63;
  int t = idx >> 5, h = idx & 31;
  const float* src = qkv + (size_t)t * QKV_OUT + (h >> 2) * 768 + (h & 3) * 128;
  float x0 = src[d], x1 = src[d + 64];
  float c0 = cosp[t * HD + d], c1 = cosp[t * HD + d + 64];
  float s0 = sinp[t * HD + d], s1 = sinp[t * HD + d + 64];
  const float SC = 0.08838834764831845f * 1.4426950408889634f;
  bf16* dst = qb + ((size_t)t * NH + h) * HD;
  dst[d]      = (bf16)((x0 * c0 - x1 * s0) * SC);
  dst[d + 64] = (bf16)((x1 * c1 + x0 * s1) * SC);
}

// ---------------- RoPE on K, write bf16 [t][kvh][d] ----------------
__global__ __launch_bounds__(256)
void rope_k(const float* __restrict__ qkv, const float* __restrict__ cosp,
            const float* __restrict__ sinp, bf16* __restrict__ kb) {
  int idx = blockIdx.x * 4 + (threadIdx.x >> 6);
  int d = threadIdx.x & 63;
  int t = idx >> 3, kvh = idx & 7;
  const float* src = qkv + (size_t)t * QKV_OUT + kvh * 768 + 512;
  float x0 = src[d], x1 = src[d + 64];
  float c0 = cosp[t * HD + d], c1 = cosp[t * HD + d + 64];
  float s0 = sinp[t * HD + d], s1 = sinp[t * HD + d + 64];
  bf16* dst = kb + ((size_t)t * NKV + kvh) * HD;
  dst[d]      = (bf16)(x0 * c0 - x1 * s0);
  dst[d + 64] = (bf16)(x1 * c1 + x0 * s1);
}

// ---------------- V transpose: qkv slot5 -> vtb[kvh][d][t] bf16 ----------------
__global__ __launch_bounds__(256)
void v_trans(const float* __restrict__ qkv, bf16* __restrict__ vtb) {
  __shared__ bf16 tile[128][72];
  const int kvh = blockIdx.y;
  const int t0 = blockIdx.x * 64;
  const int tid = threadIdx.x;
  for (int i = tid; i < 64 * 32; i += 256) {
    int t = i >> 5;
    int dq = (i & 31) * 4;
    const float* p = qkv + (size_t)(t0 + t) * QKV_OUT + kvh * 768 + 640 + dq;
    float4 v = *(const float4*)p;
    tile[dq + 0][t] = (bf16)v.x;
    tile[dq + 1][t] = (bf16)v.y;
    tile[dq + 2][t] = (bf16)v.z;
    tile[dq + 3][t] = (bf16)v.w;
  }
  __syncthreads();
  for (int i = tid; i < 128 * 8; i += 256) {
    int d = i >> 3;
    int tt = (i & 7) * 8;
    bf16x8 v;
#pragma unroll
    for (int j = 0; j < 8; ++j) v[j] = tile[d][tt + j];
    *(bf16x8*)(vtb + ((size_t)kvh * HD + d) * T_SEQ + t0 + tt) = v;
  }
}

// ---------------- cache copy + beacon-rope fill ----------------
__global__ __launch_bounds__(256)
void cache_copy(const float* __restrict__ kc, const float* __restrict__ vc,
                float* __restrict__ kout, float* __restrict__ vout) {
  int i = blockIdx.x * 256 + threadIdx.x;
  kout[i] = kc[i];
  vout[i] = vc[i];
}

__global__ __launch_bounds__(256)
void cache_fill(const float* __restrict__ qkv, const int* __restrict__ mem_idx,
                const int* __restrict__ blk_off, const float* __restrict__ bcos,
                const float* __restrict__ bsin,
                float* __restrict__ kout, float* __restrict__ vout) {
  const int m = blockIdx.x;
  const int row = mem_idx[m];
  const int blk = blk_off[m >> 6];
  const int off = m & 63;
  const int tid = threadIdx.x;
  for (int i = tid; i < NKV * 64; i += 256) {
    int kvh = i >> 6, d = i & 63;
    const float* ks = qkv + (size_t)row * QKV_OUT + kvh * 768 + 512;
    const float* vs = ks + 128;
    float x0 = ks[d], x1 = ks[d + 64];
    float c0 = bcos[m * HD + d], c1 = bcos[m * HD + d + 64];
    float s0 = bsin[m * HD + d], s1 = bsin[m * HD + d + 64];
    size_t base = (((size_t)blk * 64 + off) * NKV + kvh) * HD;
    kout[base + d]      = x0 * c0 - x1 * s0;
    kout[base + d + 64] = x1 * c1 + x0 * s1;
    vout[base + d]      = vs[d];
    vout[base + d + 64] = vs[d + 64];
  }
}

// ---------------- flash helpers ----------------
__device__ __forceinline__ uint32_t pk2(float x, float y) {
  bf16 a = (bf16)x, b = (bf16)y;
  uint16_t ua = __builtin_bit_cast(uint16_t, a), ub = __builtin_bit_cast(uint16_t, b);
  return (uint32_t)ua | ((uint32_t)ub << 16);
}

// Redistribute P^T (C-layout, chunk pair c0,c1) into the MFMA B-fragment
// (lane holds kv = lg*8..lg*8+7 for q=lr). 6 shuffles, predicated selects.
__device__ __forceinline__ bf16x8 dance(const f32x4& pc0, const f32x4& pc1, int lg) {
  uint32_t a0 = pk2(pc0[0], pc0[1]), a1 = pk2(pc0[2], pc0[3]);
  uint32_t b0 = pk2(pc1[0], pc1[1]), b1 = pk2(pc1[2], pc1[3]);
  bool lo = lg < 2;
  uint32_t k0 = lo ? a0 : b0, k1 = lo ? a1 : b1;
  uint32_t s0 = lo ? b0 : a0, s1 = lo ? b1 : a1;
  uint32_t r0 = (uint32_t)__shfl_xor((int)s0, 32, 64);
  uint32_t r1 = (uint32_t)__shfl_xor((int)s1, 32, 64);
  uint32_t tk0 = (uint32_t)__shfl_xor((int)k0, 16, 64);
  uint32_t tk1 = (uint32_t)__shfl_xor((int)k1, 16, 64);
  uint32_t tr0 = (uint32_t)__shfl_xor((int)r0, 16, 64);
  uint32_t tr1 = (uint32_t)__shfl_xor((int)r1, 16, 64);
  bool ev = !(lg & 1);
  union { uint32_t u[4]; bf16x8 v; } out;
  out.u[0] = ev ? (lo ? k0 : r0) : (lo ? tr0 : tk0);
  out.u[1] = ev ? (lo ? k1 : r1) : (lo ? tr1 : tk1);
  out.u[2] = ev ? (lo ? tk0 : tr0) : (lo ? r0 : k0);
  out.u[3] = ev ? (lo ? tk1 : tr1) : (lo ? r1 : k1);
  return out.v;
}

__device__ __forceinline__ float online_sm(f32x4 (&S)[4], float& m_r, float& l_r) {
  float pmax = S[0][0];
#pragma unroll
  for (int ch = 0; ch < 4; ++ch)
#pragma unroll
    for (int j = 0; j < 4; ++j) pmax = fmaxf(pmax, S[ch][j]);
  pmax = fmaxf(pmax, __shfl_xor(pmax, 16, 64));
  pmax = fmaxf(pmax, __shfl_xor(pmax, 32, 64));
  float mn = fmaxf(m_r, pmax);
  float corr = exp2f(m_r - mn);
  m_r = mn;
  float ps = 0.f;
#pragma unroll
  for (int ch = 0; ch < 4; ++ch)
#pragma unroll
    for (int j = 0; j < 4; ++j) {
      float p = exp2f(S[ch][j] - mn);  // masked (-1e30) underflows to 0
      S[ch][j] = p;
      ps += p;
    }
  ps += __shfl_xor(ps, 16, 64);
  ps += __shfl_xor(ps, 32, 64);
  l_r = l_r * corr + ps;
  return corr;
}

// ---------------- causal flash attention, swapped-QK^T, bf16 MFMA ----------------
// grid (16 qtiles of 128 [reversed], 32 heads), 4 waves x 32 q-rows. KV tiles of 64.
__global__ __launch_bounds__(256)
void flash(const bf16* __restrict__ qb, const bf16* __restrict__ kb,
           const bf16* __restrict__ vtb, bf16* __restrict__ attnb) {
  __shared__ bf16 Ks[64 * 128];   // [kv][d], XOR-swizzled rows (256B)
  __shared__ bf16 Vs[128 * 64];   // [d][kv], XOR-swizzled rows (128B)
  const int qt = gridDim.x - 1 - blockIdx.x;   // longest blocks dispatch first
  const int q0 = qt * 128;
  const int h = blockIdx.y;
  const int kvh = h >> 2;
  const int tid = threadIdx.x;
  const int wid = tid >> 6, lane = tid & 63;
  const int lr = lane & 15, lg = lane >> 4;
  const int qrowA = q0 + wid * 32 + lr;
  const int qrowB = qrowA + 16;

  // Q fragments (B-operand layout): Q[q=lr(+16)][d]
  bf16x8 qfA[4], qfB[4];
  {
    const bf16* qa = qb + (((size_t)qrowA) * NH + h) * HD + lg * 8;
    const bf16* qc = qb + (((size_t)qrowB) * NH + h) * HD + lg * 8;
#pragma unroll
    for (int kk = 0; kk < 4; ++kk) {
      qfA[kk] = *(const bf16x8*)(qa + kk * 32);
      qfB[kk] = *(const bf16x8*)(qc + kk * 32);
    }
  }
  f32x4 oA[8] = {}, oB[8] = {};
  float mA = -1e30f, lA = 0.f, mB = -1e30f, lB = 0.f;

  // staging decomposition (K: 4 rows of 256B per issue; V: 8 rows of 128B per issue)
  const int k_r0 = wid * 16 + lg;
  const int k_cb = lr * 16;
  const int v_r0 = wid * 32 + (lane >> 3);
  const int v_cb = (lane & 7) * 16;

  const int kv_end = q0 + 128;
  for (int jt = 0; jt < kv_end; jt += 64) {
#pragma unroll
    for (int i = 0; i < 4; ++i) {
      const int krow = k_r0 + i * 4;
      g2l16(kb + ((size_t)(jt + krow) * NKV + kvh) * HD + ((k_cb ^ ((krow & 7) << 4)) >> 1),
            Ks + wid * 2048 + i * 512);
      const int vrow = v_r0 + i * 8;
      g2l16(vtb + ((size_t)kvh * HD + vrow) * T_SEQ + jt + ((v_cb ^ ((vrow & 7) << 4)) >> 1),
            Vs + wid * 2048 + i * 512);
    }
    __syncthreads();
    if (jt <= q0 + wid * 32 + 31) {  // wave-uniform: tile not fully masked
      const char* KsB = (const char*)Ks;
      f32x4 SA[4] = {}, SB[4] = {};
#pragma unroll
      for (int ch = 0; ch < 4; ++ch) {
        const int row = ch * 16 + lr;
        const char* rb = KsB + row * 256;
        const int swz = (row & 7) << 4;
#pragma unroll
        for (int kk = 0; kk < 4; ++kk) {
          bf16x8 kf = *(const bf16x8*)(rb + ((kk * 64 + lg * 16) ^ swz));
          SA[ch] = __builtin_amdgcn_mfma_f32_16x16x32_bf16(kf, qfA[kk], SA[ch], 0, 0, 0);
          SB[ch] = __builtin_amdgcn_mfma_f32_16x16x32_bf16(kf, qfB[kk], SB[ch], 0, 0, 0);
        }
      }
      if (jt + 63 > q0 + wid * 32) {  // diagonal tile: apply causal mask
#pragma unroll
        for (int ch = 0; ch < 4; ++ch)
#pragma unroll
          for (int j = 0; j < 4; ++j) {
            const int kv = jt + ch * 16 + lg * 4 + j;
            if (kv > qrowA) SA[ch][j] = -1e30f;
            if (kv > qrowB) SB[ch][j] = -1e30f;
          }
      }
      float corrA = online_sm(SA, mA, lA);
      float corrB = online_sm(SB, mB, lB);
#pragma unroll
      for (int db = 0; db < 8; ++db) { oA[db] *= corrA; oB[db] *= corrB; }
      bf16x8 pbA[2], pbB[2];
#pragma unroll
      for (int ks = 0; ks < 2; ++ks) {
        pbA[ks] = dance(SA[2 * ks], SA[2 * ks + 1], lg);
        pbB[ks] = dance(SB[2 * ks], SB[2 * ks + 1], lg);
      }
      const char* VsB = (const char*)Vs;
#pragma unroll
      for (int db = 0; db < 8; ++db) {
        const int row = db * 16 + lr;
        const char* rb = VsB + row * 128;
        const int swz = (row & 7) << 4;
#pragma unroll
        for (int ks = 0; ks < 2; ++ks) {
          bf16x8 vf = *(const bf16x8*)(rb + ((ks * 64 + lg * 16) ^ swz));
          oA[db] = __builtin_amdgcn_mfma_f32_16x16x32_bf16(vf, pbA[ks], oA[db], 0, 0, 0);
          oB[db] = __builtin_amdgcn_mfma_f32_16x16x32_bf16(vf, pbB[ks], oB[db], 0, 0, 0);
        }
      }
    }
    __syncthreads();
  }
  const float invA = 1.f / lA, invB = 1.f / lB;
#pragma unroll
  for (int db = 0; db < 8; ++db) {
    bf16x4 wA, wB;
#pragma unroll
    for (int j = 0; j < 4; ++j) {
      wA[j] = (bf16)(oA[db][j] * invA);
      wB[j] = (bf16)(oB[db][j] * invB);
    }
    *(bf16x4*)(attnb + (size_t)qrowA * HDIM + h * HD + db * 16 + lg * 4) = wA;
    *(bf16x4*)(attnb + (size_t)qrowB * HDIM + h * HD + db * 16 + lg * 4) = wB;
  }
}

// ---------------- launcher ----------------
extern "C" void kernel_launch(void* const* d_in, const int* in_sizes, int n_in,
                              void* d_out, int out_size, void* d_ws, size_t ws_size,
                              hipStream_t stream) {
  (void)in_sizes; (void)n_in; (void)out_size; (void)ws_size;
  const float* hidden  = (const float*)d_in[0];
  const float* cosp    = (const float*)d_in[1];
  const float* sinp    = (const float*)d_in[2];
  const float* bcos    = (const float*)d_in[3];
  const float* bsin    = (const float*)d_in[4];
  const int*   mem_idx = (const int*)d_in[5];
  const int*   im_idx  = (const int*)d_in[6];
  const float* kc_in   = (const float*)d_in[7];
  const float* vc_in   = (const float*)d_in[8];
  const int*   blk_off = (const int*)d_in[9];
  const float* wqkv_w  = (const float*)d_in[10];
  const float* wqkv_A  = (const float*)d_in[11];
  const float* wqkv_B  = (const float*)d_in[12];
  const float* wqkv_MA = (const float*)d_in[13];
  const float* wqkv_MB = (const float*)d_in[14];
  const float* wo_w    = (const float*)d_in[15];
  const float* wo_A    = (const float*)d_in[16];
  const float* wo_B    = (const float*)d_in[17];
  const float* wo_MA   = (const float*)d_in[18];
  const float* wo_MB   = (const float*)d_in[19];

  char* ws = (char*)d_ws;
  size_t off = 0;
  auto alloc = [&](size_t b) { char* p = ws + off; off += (b + 255) & ~(size_t)255; return p; };
  bf16* xb    = (bf16*)alloc(2048ull * 4096 * 2);
  bf16* wqkvb = (bf16*)alloc(6144ull * 4096 * 2);
  bf16* wob   = (bf16*)alloc(4096ull * 4096 * 2);
  bf16* qAb   = (bf16*)alloc(256ull * 4096 * 2);
  bf16* qBb   = (bf16*)alloc(6144ull * 256 * 2);
  bf16* qMAb  = (bf16*)alloc(256ull * 4096 * 2);
  bf16* qMBb  = (bf16*)alloc(6144ull * 256 * 2);
  bf16* oAb   = (bf16*)alloc(256ull * 4096 * 2);
  bf16* oBb   = (bf16*)alloc(4096ull * 256 * 2);
  bf16* oMAb  = (bf16*)alloc(256ull * 4096 * 2);
  bf16* oMBb  = (bf16*)alloc(4096ull * 256 * 2);
  float* qkv  = (float*)alloc(2048ull * 6144 * 4);
  bf16* qb    = (bf16*)alloc(2048ull * 32 * 128 * 2);
  bf16* kbuf  = (bf16*)alloc(2048ull * 8 * 128 * 2);
  bf16* vtb   = (bf16*)alloc(8ull * 128 * 2048 * 2);
  bf16* attnb = (bf16*)alloc(2048ull * 4096 * 2);
  float* tf   = (float*)alloc(1280ull * 256 * 4);
  bf16* tb    = (bf16*)alloc(1280ull * 256 * 2);
  float* t_im_f  = tf;               float* t_mem_f  = tf + 512 * 256;
  float* t2_im_f = tf + 640 * 256;   float* t2_mem_f = tf + 1152 * 256;
  bf16* t_im_b   = tb;               bf16* t_mem_b   = tb + 512 * 256;
  bf16* t2_im_b  = tb + 640 * 256;   bf16* t2_mem_b  = tb + 1152 * 256;
  (void)t_mem_f; (void)t2_mem_f;

  float* outp   = (float*)d_out;
  float* kc_out = outp + 2048ull * 4096;
  float* vc_out = kc_out + 4ull * 64 * 8 * 128;

  auto cvt = [&](const float* src, bf16* dst, size_t n) {
    size_t g = (n / 8 + 255) / 256;
    if (g > 2048) g = 2048;
    cvt_kernel<<<(unsigned)g, 256, 0, stream>>>(src, dst, (int)n);
  };
  cvt(hidden, xb, 2048ull * 4096);
  cvt(wqkv_w, wqkvb, 6144ull * 4096);
  cvt(wo_w, wob, 4096ull * 4096);
  cvt(wqkv_A, qAb, 256ull * 4096);
  cvt(wqkv_B, qBb, 6144ull * 256);
  cvt(wqkv_MA, qMAb, 256ull * 4096);
  cvt(wqkv_MB, qMBb, 6144ull * 256);
  cvt(wo_A, oAb, 256ull * 4096);
  cvt(wo_B, oBb, 4096ull * 256);
  cvt(wo_MA, oMAb, 256ull * 4096);
  cvt(wo_MB, oMBb, 4096ull * 256);
  zero_f32<<<1280, 256, 0, stream>>>(tf, 1280 * 256);

  // qkv = x @ wqkv^T (+ LoRA scatter-adds)
  gemm128<<<dim3(16, 48), 256, 0, stream>>>(xb, wqkvb, qkv, 2048, 6144, 4096);
  gemm64<1, 2><<<dim3(8, 4, 8), 256, 0, stream>>>(xb, qAb, im_idx, nullptr, nullptr, t_im_f, 512, 256, 4096, 256, 1.f);
  gemm64<1, 2><<<dim3(2, 4, 8), 256, 0, stream>>>(xb, qMAb, mem_idx, nullptr, nullptr, t_mem_f, 128, 256, 4096, 256, 1.f);
  cvt(tf, tb, 640 * 256);
  gemm64<0, 1><<<dim3(8, 96), 256, 0, stream>>>(t_im_b, qBb, nullptr, im_idx, nullptr, qkv, 512, 6144, 256, 6144, 1.f);
  gemm64<0, 1><<<dim3(2, 96), 256, 0, stream>>>(t_mem_b, qMBb, nullptr, mem_idx, nullptr, qkv, 128, 6144, 256, 6144, 1.f);

  // rope / extract / cache
  rope_q<<<16384, 256, 0, stream>>>(qkv, cosp, sinp, qb);
  rope_k<<<4096, 256, 0, stream>>>(qkv, cosp, sinp, kbuf);
  v_trans<<<dim3(32, 8), 256, 0, stream>>>(qkv, vtb);
  cache_copy<<<1024, 256, 0, stream>>>(kc_in, vc_in, kc_out, vc_out);
  cache_fill<<<128, 256, 0, stream>>>(qkv, mem_idx, blk_off, bcos, bsin, kc_out, vc_out);

  // attention
  flash<<<dim3(16, 32), 256, 0, stream>>>(qb, kbuf, vtb, attnb);

  // out = attn @ wo^T (+ LoRA scatter-adds)
  gemm128<<<dim3(16, 32), 256, 0, stream>>>(attnb, wob, outp, 2048, 4096, 4096);
  gemm64<1, 2><<<dim3(8, 4, 8), 256, 0, stream>>>(attnb, oAb, im_idx, nullptr, nullptr, t2_im_f, 512, 256, 4096, 256, 1.f);
  gemm64<1, 2><<<dim3(2, 4, 8), 256, 0, stream>>>(attnb, oMAb, mem_idx, nullptr, nullptr, t2_mem_f, 128, 256, 4096, 256, 1.f);
  cvt(t2_im_f, t2_im_b, 640 * 256);
  gemm64<0, 1><<<dim3(8, 64), 256, 0, stream>>>(t2_im_b, oBb, nullptr, im_idx, nullptr, outp, 512, 4096, 256, 4096, 1.f);
  gemm64<0, 1><<<dim3(2, 64), 256, 0, stream>>>(t2_mem_b, oMBb, nullptr, mem_idx, nullptr, outp, 128, 4096, 256, 4096, 1.f);
}

// Round 8
// 762.360 us; speedup vs baseline: 1.1978x; 1.1573x over previous
//
#include <hip/hip_runtime.h>
#include <hip/hip_bf16.h>
#include <stdint.h>

typedef __bf16 bf16;
typedef __bf16 bf16x8 __attribute__((ext_vector_type(8)));
typedef __bf16 bf16x4 __attribute__((ext_vector_type(4)));
typedef float f32x4 __attribute__((ext_vector_type(4)));

#define T_SEQ 2048
#define NH 32
#define NKV 8
#define HD 128
#define HDIM 4096
#define QKV_OUT 6144

__device__ __forceinline__ void g2l16(const void* g, void* l) {
  __builtin_amdgcn_global_load_lds(
      (const __attribute__((address_space(1))) void*)g,
      (__attribute__((address_space(3))) void*)l, 16, 0, 0);
}

// ---------------- f32 -> bf16 convert ----------------
__global__ __launch_bounds__(256) void cvt_kernel(const float* __restrict__ in,
                                                  bf16* __restrict__ out, int n) {
  int stride = gridDim.x * blockDim.x * 8;
  for (int i = (blockIdx.x * blockDim.x + threadIdx.x) * 8; i < n; i += stride) {
    float4 a = *(const float4*)(in + i);
    float4 b = *(const float4*)(in + i + 4);
    bf16x8 o;
    o[0] = (bf16)a.x; o[1] = (bf16)a.y; o[2] = (bf16)a.z; o[3] = (bf16)a.w;
    o[4] = (bf16)b.x; o[5] = (bf16)b.y; o[6] = (bf16)b.z; o[7] = (bf16)b.w;
    *(bf16x8*)(out + i) = o;
  }
}

__global__ __launch_bounds__(256) void zero_f32(float* __restrict__ p, int n) {
  int i = blockIdx.x * 256 + threadIdx.x;
  if (i < n) p[i] = 0.f;
}

// ---------------- 128x128 bf16 MFMA GEMM (m97 structure): C = A @ B^T ----------------
__global__ __launch_bounds__(256)
void gemm128(const bf16* __restrict__ A, const bf16* __restrict__ B,
             float* __restrict__ C, int M, int N, int K) {
  __shared__ bf16 As[128 * 32];
  __shared__ bf16 Bs[128 * 32];
  const int tid = threadIdx.x;
  const int wid = tid >> 6, lane = tid & 63;
  const int bm = blockIdx.x * 128, bn = blockIdx.y * 128;
  const int wr = (wid >> 1) * 64, wc = (wid & 1) * 64;
  const int lr = lane & 15, lk = (lane >> 4) * 8;
  const int srow = wid * 32 + (lane >> 2);
  const int scol = (lane & 3) * 8;
  const bf16* Ag = A + (size_t)(bm + srow) * K + scol;
  const bf16* Bg = B + (size_t)(bn + srow) * K + scol;
  bf16* Al = As + wid * 1024;
  bf16* Bl = Bs + wid * 1024;
  f32x4 acc[4][4] = {};
  for (int k0 = 0; k0 < K; k0 += 32) {
    g2l16(Ag + k0, Al);
    g2l16(Ag + k0 + (size_t)16 * K, Al + 512);
    g2l16(Bg + k0, Bl);
    g2l16(Bg + k0 + (size_t)16 * K, Bl + 512);
    __syncthreads();
    bf16x8 af[4], bfv[4];
#pragma unroll
    for (int m = 0; m < 4; ++m)
      af[m] = *(const bf16x8*)(As + (wr + m * 16 + lr) * 32 + lk);
#pragma unroll
    for (int n = 0; n < 4; ++n)
      bfv[n] = *(const bf16x8*)(Bs + (wc + n * 16 + lr) * 32 + lk);
#pragma unroll
    for (int m = 0; m < 4; ++m)
#pragma unroll
      for (int n = 0; n < 4; ++n)
        acc[m][n] = __builtin_amdgcn_mfma_f32_16x16x32_bf16(af[m], bfv[n], acc[m][n], 0, 0, 0);
    __syncthreads();
  }
  const int orow = (lane >> 4) * 4;
#pragma unroll
  for (int m = 0; m < 4; ++m)
#pragma unroll
    for (int n = 0; n < 4; ++n)
#pragma unroll
      for (int j = 0; j < 4; ++j)
        C[(size_t)(bm + wr + m * 16 + orow + j) * N + (bn + wc + n * 16 + lr)] = acc[m][n][j];
}

// ---------------- 64x64 LoRA GEMM ----------------
template <int GATHER_A, int MODE>
__global__ __launch_bounds__(256)
void gemm64(const bf16* __restrict__ A, const bf16* __restrict__ B,
            const int* __restrict__ aidx, const int* __restrict__ cidx,
            bf16* __restrict__ outb, float* __restrict__ outf,
            int M, int N, int K, int ldc, float alpha) {
  __shared__ bf16 As[64 * 32];
  __shared__ bf16 Bs[64 * 32];
  const int tid = threadIdx.x;
  const int wid = tid >> 6, lane = tid & 63;
  const int bm = blockIdx.x * 64, bn = blockIdx.y * 64;
  const int wr = (wid >> 1) * 32, wc = (wid & 1) * 32;
  const int lr = lane & 15, lk = (lane >> 4) * 8;
  int arow = bm + wid * 16 + (lane >> 2);
  if (GATHER_A) arow = aidx[arow];
  const int scol = (lane & 3) * 8;
  const bf16* Ag = A + (size_t)arow * K + scol;
  const bf16* Bg = B + (size_t)(bn + wid * 16 + (lane >> 2)) * K + scol;
  bf16* Al = As + wid * 512;
  bf16* Bl = Bs + wid * 512;
  int kbeg = 0, kend = K;
  if (MODE == 2) { int kc = K / gridDim.z; kbeg = blockIdx.z * kc; kend = kbeg + kc; }
  f32x4 acc[2][2] = {};
  for (int k0 = kbeg; k0 < kend; k0 += 32) {
    g2l16(Ag + k0, Al);
    g2l16(Bg + k0, Bl);
    __syncthreads();
    bf16x8 af[2], bfv[2];
#pragma unroll
    for (int m = 0; m < 2; ++m)
      af[m] = *(const bf16x8*)(As + (wr + m * 16 + lr) * 32 + lk);
#pragma unroll
    for (int n = 0; n < 2; ++n)
      bfv[n] = *(const bf16x8*)(Bs + (wc + n * 16 + lr) * 32 + lk);
#pragma unroll
    for (int m = 0; m < 2; ++m)
#pragma unroll
      for (int n = 0; n < 2; ++n)
        acc[m][n] = __builtin_amdgcn_mfma_f32_16x16x32_bf16(af[m], bfv[n], acc[m][n], 0, 0, 0);
    __syncthreads();
  }
  const int orow = (lane >> 4) * 4;
#pragma unroll
  for (int m = 0; m < 2; ++m)
#pragma unroll
    for (int n = 0; n < 2; ++n)
#pragma unroll
      for (int j = 0; j < 4; ++j) {
        int r = bm + wr + m * 16 + orow + j;
        int c = bn + wc + n * 16 + lr;
        float v = acc[m][n][j];
        if (MODE == 0)      outb[(size_t)r * ldc + c] = (bf16)(v * alpha);
        else if (MODE == 1) atomicAdd(outf + (size_t)cidx[r] * ldc + c, v * alpha);
        else                atomicAdd(outf + (size_t)r * ldc + c, v);
      }
}

// ---------------- RoPE on Q (fold softmax scale * log2e), write bf16 [t][h][d] ----------------
__global__ __launch_bounds__(256)
void rope_q(const float* __restrict__ qkv, const float* __restrict__ cosp,
            const float* __restrict__ sinp, bf16* __restrict__ qb) {
  int idx = blockIdx.x * 4 + (threadIdx.x >> 6);
  int d = threadIdx.x & 63;
  int t = idx >> 5, h = idx & 31;
  const float* src = qkv + (size_t)t * QKV_OUT + (h >> 2) * 768 + (h & 3) * 128;
  float x0 = src[d], x1 = src[d + 64];
  float c0 = cosp[t * HD + d], c1 = cosp[t * HD + d + 64];
  float s0 = sinp[t * HD + d], s1 = sinp[t * HD + d + 64];
  const float SC = 0.08838834764831845f * 1.4426950408889634f;
  bf16* dst = qb + ((size_t)t * NH + h) * HD;
  dst[d]      = (bf16)((x0 * c0 - x1 * s0) * SC);
  dst[d + 64] = (bf16)((x1 * c1 + x0 * s1) * SC);
}

// ---------------- RoPE on K, write bf16 [t][kvh][d] ----------------
__global__ __launch_bounds__(256)
void rope_k(const float* __restrict__ qkv, const float* __restrict__ cosp,
            const float* __restrict__ sinp, bf16* __restrict__ kb) {
  int idx = blockIdx.x * 4 + (threadIdx.x >> 6);
  int d = threadIdx.x & 63;
  int t = idx >> 3, kvh = idx & 7;
  const float* src = qkv + (size_t)t * QKV_OUT + kvh * 768 + 512;
  float x0 = src[d], x1 = src[d + 64];
  float c0 = cosp[t * HD + d], c1 = cosp[t * HD + d + 64];
  float s0 = sinp[t * HD + d], s1 = sinp[t * HD + d + 64];
  bf16* dst = kb + ((size_t)t * NKV + kvh) * HD;
  dst[d]      = (bf16)(x0 * c0 - x1 * s0);
  dst[d + 64] = (bf16)(x1 * c1 + x0 * s1);
}

// ---------------- V transpose: qkv slot5 -> vtb[kvh][d][t] bf16 ----------------
__global__ __launch_bounds__(256)
void v_trans(const float* __restrict__ qkv, bf16* __restrict__ vtb) {
  __shared__ bf16 tile[128][72];
  const int kvh = blockIdx.y;
  const int t0 = blockIdx.x * 64;
  const int tid = threadIdx.x;
  for (int i = tid; i < 64 * 32; i += 256) {
    int t = i >> 5;
    int dq = (i & 31) * 4;
    const float* p = qkv + (size_t)(t0 + t) * QKV_OUT + kvh * 768 + 640 + dq;
    float4 v = *(const float4*)p;
    tile[dq + 0][t] = (bf16)v.x;
    tile[dq + 1][t] = (bf16)v.y;
    tile[dq + 2][t] = (bf16)v.z;
    tile[dq + 3][t] = (bf16)v.w;
  }
  __syncthreads();
  for (int i = tid; i < 128 * 8; i += 256) {
    int d = i >> 3;
    int tt = (i & 7) * 8;
    bf16x8 v;
#pragma unroll
    for (int j = 0; j < 8; ++j) v[j] = tile[d][tt + j];
    *(bf16x8*)(vtb + ((size_t)kvh * HD + d) * T_SEQ + t0 + tt) = v;
  }
}

// ---------------- cache copy + beacon-rope fill ----------------
__global__ __launch_bounds__(256)
void cache_copy(const float* __restrict__ kc, const float* __restrict__ vc,
                float* __restrict__ kout, float* __restrict__ vout) {
  int i = blockIdx.x * 256 + threadIdx.x;
  kout[i] = kc[i];
  vout[i] = vc[i];
}

__global__ __launch_bounds__(256)
void cache_fill(const float* __restrict__ qkv, const int* __restrict__ mem_idx,
                const int* __restrict__ blk_off, const float* __restrict__ bcos,
                const float* __restrict__ bsin,
                float* __restrict__ kout, float* __restrict__ vout) {
  const int m = blockIdx.x;
  const int row = mem_idx[m];
  const int blk = blk_off[m >> 6];
  const int off = m & 63;
  const int tid = threadIdx.x;
  for (int i = tid; i < NKV * 64; i += 256) {
    int kvh = i >> 6, d = i & 63;
    const float* ks = qkv + (size_t)row * QKV_OUT + kvh * 768 + 512;
    const float* vs = ks + 128;
    float x0 = ks[d], x1 = ks[d + 64];
    float c0 = bcos[m * HD + d], c1 = bcos[m * HD + d + 64];
    float s0 = bsin[m * HD + d], s1 = bsin[m * HD + d + 64];
    size_t base = (((size_t)blk * 64 + off) * NKV + kvh) * HD;
    kout[base + d]      = x0 * c0 - x1 * s0;
    kout[base + d + 64] = x1 * c1 + x0 * s1;
    vout[base + d]      = vs[d];
    vout[base + d + 64] = vs[d + 64];
  }
}

// ---------------- flash helpers ----------------
__device__ __forceinline__ uint32_t pk2(float x, float y) {
  bf16 a = (bf16)x, b = (bf16)y;
  uint16_t ua = __builtin_bit_cast(uint16_t, a), ub = __builtin_bit_cast(uint16_t, b);
  return (uint32_t)ua | ((uint32_t)ub << 16);
}

// Redistribute P^T (C-layout, chunk pair c0,c1) into the MFMA B-fragment
// (lane holds kv = lg*8..lg*8+7 for q=lr). 6 shuffles, predicated selects.
__device__ __forceinline__ bf16x8 dance(const f32x4& pc0, const f32x4& pc1, int lg) {
  uint32_t a0 = pk2(pc0[0], pc0[1]), a1 = pk2(pc0[2], pc0[3]);
  uint32_t b0 = pk2(pc1[0], pc1[1]), b1 = pk2(pc1[2], pc1[3]);
  bool lo = lg < 2;
  uint32_t k0 = lo ? a0 : b0, k1 = lo ? a1 : b1;
  uint32_t s0 = lo ? b0 : a0, s1 = lo ? b1 : a1;
  uint32_t r0 = (uint32_t)__shfl_xor((int)s0, 32, 64);
  uint32_t r1 = (uint32_t)__shfl_xor((int)s1, 32, 64);
  uint32_t tk0 = (uint32_t)__shfl_xor((int)k0, 16, 64);
  uint32_t tk1 = (uint32_t)__shfl_xor((int)k1, 16, 64);
  uint32_t tr0 = (uint32_t)__shfl_xor((int)r0, 16, 64);
  uint32_t tr1 = (uint32_t)__shfl_xor((int)r1, 16, 64);
  bool ev = !(lg & 1);
  union { uint32_t u[4]; bf16x8 v; } out;
  out.u[0] = ev ? (lo ? k0 : r0) : (lo ? tr0 : tk0);
  out.u[1] = ev ? (lo ? k1 : r1) : (lo ? tr1 : tk1);
  out.u[2] = ev ? (lo ? tk0 : tr0) : (lo ? r0 : k0);
  out.u[3] = ev ? (lo ? tk1 : tr1) : (lo ? r1 : k1);
  return out.v;
}

__device__ __forceinline__ float online_sm(f32x4 (&S)[4], float& m_r, float& l_r) {
  float pmax = S[0][0];
#pragma unroll
  for (int ch = 0; ch < 4; ++ch)
#pragma unroll
    for (int j = 0; j < 4; ++j) pmax = fmaxf(pmax, S[ch][j]);
  pmax = fmaxf(pmax, __shfl_xor(pmax, 16, 64));
  pmax = fmaxf(pmax, __shfl_xor(pmax, 32, 64));
  float mn = fmaxf(m_r, pmax);
  float corr = exp2f(m_r - mn);
  m_r = mn;
  float ps = 0.f;
#pragma unroll
  for (int ch = 0; ch < 4; ++ch)
#pragma unroll
    for (int j = 0; j < 4; ++j) {
      float p = exp2f(S[ch][j] - mn);  // masked (-1e30) underflows to 0
      S[ch][j] = p;
      ps += p;
    }
  ps += __shfl_xor(ps, 16, 64);
  ps += __shfl_xor(ps, 32, 64);
  l_r = l_r * corr + ps;
  return corr;
}

// ---------------- causal flash attention, diagonal-paired, double-buffered ----------------
// grid (8, 32), 8 waves x 512 thr. Block b: qtiles {b, 15-b} (uniform work).
// Wave owns 16 rows of each tile. KV tiles of 64, 2-phase prefetch pipeline.
__global__ __launch_bounds__(512, 2)
void flash(const bf16* __restrict__ qb, const bf16* __restrict__ kb,
           const bf16* __restrict__ vtb, bf16* __restrict__ attnb) {
  __shared__ bf16 Ks[2][64 * 128];   // [kv][d], swizzled rows (256B)
  __shared__ bf16 Vs[2][128 * 64];   // [d][kv], swizzled rows (128B)
  const int qt_lo = blockIdx.x, qt_hi = 15 - blockIdx.x;
  const int q0L = qt_lo * 128, q0H = qt_hi * 128;
  const int h = blockIdx.y, kvh = h >> 2;
  const int tid = threadIdx.x;
  const int wid = tid >> 6, lane = tid & 63;
  const int lr = lane & 15, lg = lane >> 4;
  const int qrowL = q0L + wid * 16 + lr;
  const int qrowH = q0H + wid * 16 + lr;

  bf16x8 qfL[4], qfH[4];
  {
    const bf16* qa = qb + ((size_t)qrowL * NH + h) * HD + lg * 8;
    const bf16* qc = qb + ((size_t)qrowH * NH + h) * HD + lg * 8;
#pragma unroll
    for (int kk = 0; kk < 4; ++kk) {
      qfL[kk] = *(const bf16x8*)(qa + kk * 32);
      qfH[kk] = *(const bf16x8*)(qc + kk * 32);
    }
  }
  f32x4 oL[8] = {}, oH[8] = {};
  float mL = -1e30f, lL = 0.f, mH = -1e30f, lH = 0.f;

  const int k_cb = lr * 16;
  const int v_cb = (lane & 7) * 16;
  const int kr_b = wid * 8 + lg;          // + 4*i
  const int vr_b = wid * 16 + (lane >> 3); // + 8*i
  const int nt = (qt_hi + 1) * 2;

  auto STAGE = [&](int buf, int jt) {
#pragma unroll
    for (int i = 0; i < 2; ++i) {
      const int krow = kr_b + i * 4;
      g2l16(kb + ((size_t)(jt + krow) * NKV + kvh) * HD + ((k_cb ^ ((krow & 7) << 4)) >> 1),
            &Ks[buf][wid * 1024 + i * 512]);
      const int vrow = vr_b + i * 8;
      g2l16(vtb + ((size_t)kvh * HD + vrow) * T_SEQ + jt + ((v_cb ^ ((vrow & 7) << 4)) >> 1),
            &Vs[buf][wid * 1024 + i * 512]);
    }
  };

  STAGE(0, 0);
  __syncthreads();
  int cur = 0;
  for (int t = 0; t < nt; ++t) {
    const int jt = t * 64;
    if (t + 1 < nt) STAGE(cur ^ 1, jt + 64);   // prefetch hides under compute
    const bool doL = (jt <= q0L + wid * 16 + 15);
    const bool doH = (jt <= q0H + wid * 16 + 15);
    const char* KsB = (const char*)Ks[cur];
    const char* VsB = (const char*)Vs[cur];
    if (doL) {  // doL implies doH: compute both tiles, kf/vf reads shared
      f32x4 SL[4] = {}, SH[4] = {};
#pragma unroll
      for (int ch = 0; ch < 4; ++ch) {
        const int row = ch * 16 + lr;
        const char* rb = KsB + row * 256;
        const int swz = (row & 7) << 4;
#pragma unroll
        for (int kk = 0; kk < 4; ++kk) {
          bf16x8 kf = *(const bf16x8*)(rb + ((kk * 64 + lg * 16) ^ swz));
          SL[ch] = __builtin_amdgcn_mfma_f32_16x16x32_bf16(kf, qfL[kk], SL[ch], 0, 0, 0);
          SH[ch] = __builtin_amdgcn_mfma_f32_16x16x32_bf16(kf, qfH[kk], SH[ch], 0, 0, 0);
        }
      }
      if (jt + 63 > q0L + wid * 16) {  // L diagonal; H never masked here (q0H >= q0L+128)
#pragma unroll
        for (int ch = 0; ch < 4; ++ch)
#pragma unroll
          for (int j = 0; j < 4; ++j)
            if (jt + ch * 16 + lg * 4 + j > qrowL) SL[ch][j] = -1e30f;
      }
      float corrL = online_sm(SL, mL, lL);
      float corrH = online_sm(SH, mH, lH);
#pragma unroll
      for (int db = 0; db < 8; ++db) { oL[db] *= corrL; oH[db] *= corrH; }
      bf16x8 pbL[2], pbH[2];
#pragma unroll
      for (int ks = 0; ks < 2; ++ks) {
        pbL[ks] = dance(SL[2 * ks], SL[2 * ks + 1], lg);
        pbH[ks] = dance(SH[2 * ks], SH[2 * ks + 1], lg);
      }
#pragma unroll
      for (int db = 0; db < 8; ++db) {
        const int row = db * 16 + lr;
        const char* rb = VsB + row * 128;
        const int swz = (row & 7) << 4;
#pragma unroll
        for (int ks = 0; ks < 2; ++ks) {
          bf16x8 vf = *(const bf16x8*)(rb + ((ks * 64 + lg * 16) ^ swz));
          oL[db] = __builtin_amdgcn_mfma_f32_16x16x32_bf16(vf, pbL[ks], oL[db], 0, 0, 0);
          oH[db] = __builtin_amdgcn_mfma_f32_16x16x32_bf16(vf, pbH[ks], oH[db], 0, 0, 0);
        }
      }
    } else if (doH) {  // H-only region
      f32x4 SH[4] = {};
#pragma unroll
      for (int ch = 0; ch < 4; ++ch) {
        const int row = ch * 16 + lr;
        const char* rb = KsB + row * 256;
        const int swz = (row & 7) << 4;
#pragma unroll
        for (int kk = 0; kk < 4; ++kk) {
          bf16x8 kf = *(const bf16x8*)(rb + ((kk * 64 + lg * 16) ^ swz));
          SH[ch] = __builtin_amdgcn_mfma_f32_16x16x32_bf16(kf, qfH[kk], SH[ch], 0, 0, 0);
        }
      }
      if (jt + 63 > q0H + wid * 16) {
#pragma unroll
        for (int ch = 0; ch < 4; ++ch)
#pragma unroll
          for (int j = 0; j < 4; ++j)
            if (jt + ch * 16 + lg * 4 + j > qrowH) SH[ch][j] = -1e30f;
      }
      float corrH = online_sm(SH, mH, lH);
#pragma unroll
      for (int db = 0; db < 8; ++db) oH[db] *= corrH;
      bf16x8 pbH[2];
#pragma unroll
      for (int ks = 0; ks < 2; ++ks) pbH[ks] = dance(SH[2 * ks], SH[2 * ks + 1], lg);
#pragma unroll
      for (int db = 0; db < 8; ++db) {
        const int row = db * 16 + lr;
        const char* rb = VsB + row * 128;
        const int swz = (row & 7) << 4;
#pragma unroll
        for (int ks = 0; ks < 2; ++ks) {
          bf16x8 vf = *(const bf16x8*)(rb + ((ks * 64 + lg * 16) ^ swz));
          oH[db] = __builtin_amdgcn_mfma_f32_16x16x32_bf16(vf, pbH[ks], oH[db], 0, 0, 0);
        }
      }
    }
    __syncthreads();   // drains prefetch (compiler vmcnt) + protects buf reuse
    cur ^= 1;
  }
  const float invL = 1.f / lL, invH = 1.f / lH;
#pragma unroll
  for (int db = 0; db < 8; ++db) {
    bf16x4 wL, wH;
#pragma unroll
    for (int j = 0; j < 4; ++j) {
      wL[j] = (bf16)(oL[db][j] * invL);
      wH[j] = (bf16)(oH[db][j] * invH);
    }
    *(bf16x4*)(attnb + (size_t)qrowL * HDIM + h * HD + db * 16 + lg * 4) = wL;
    *(bf16x4*)(attnb + (size_t)qrowH * HDIM + h * HD + db * 16 + lg * 4) = wH;
  }
}

// ---------------- launcher ----------------
extern "C" void kernel_launch(void* const* d_in, const int* in_sizes, int n_in,
                              void* d_out, int out_size, void* d_ws, size_t ws_size,
                              hipStream_t stream) {
  (void)in_sizes; (void)n_in; (void)out_size; (void)ws_size;
  const float* hidden  = (const float*)d_in[0];
  const float* cosp    = (const float*)d_in[1];
  const float* sinp    = (const float*)d_in[2];
  const float* bcos    = (const float*)d_in[3];
  const float* bsin    = (const float*)d_in[4];
  const int*   mem_idx = (const int*)d_in[5];
  const int*   im_idx  = (const int*)d_in[6];
  const float* kc_in   = (const float*)d_in[7];
  const float* vc_in   = (const float*)d_in[8];
  const int*   blk_off = (const int*)d_in[9];
  const float* wqkv_w  = (const float*)d_in[10];
  const float* wqkv_A  = (const float*)d_in[11];
  const float* wqkv_B  = (const float*)d_in[12];
  const float* wqkv_MA = (const float*)d_in[13];
  const float* wqkv_MB = (const float*)d_in[14];
  const float* wo_w    = (const float*)d_in[15];
  const float* wo_A    = (const float*)d_in[16];
  const float* wo_B    = (const float*)d_in[17];
  const float* wo_MA   = (const float*)d_in[18];
  const float* wo_MB   = (const float*)d_in[19];

  char* ws = (char*)d_ws;
  size_t off = 0;
  auto alloc = [&](size_t b) { char* p = ws + off; off += (b + 255) & ~(size_t)255; return p; };
  bf16* xb    = (bf16*)alloc(2048ull * 4096 * 2);
  bf16* wqkvb = (bf16*)alloc(6144ull * 4096 * 2);
  bf16* wob   = (bf16*)alloc(4096ull * 4096 * 2);
  bf16* qAb   = (bf16*)alloc(256ull * 4096 * 2);
  bf16* qBb   = (bf16*)alloc(6144ull * 256 * 2);
  bf16* qMAb  = (bf16*)alloc(256ull * 4096 * 2);
  bf16* qMBb  = (bf16*)alloc(6144ull * 256 * 2);
  bf16* oAb   = (bf16*)alloc(256ull * 4096 * 2);
  bf16* oBb   = (bf16*)alloc(4096ull * 256 * 2);
  bf16* oMAb  = (bf16*)alloc(256ull * 4096 * 2);
  bf16* oMBb  = (bf16*)alloc(4096ull * 256 * 2);
  float* qkv  = (float*)alloc(2048ull * 6144 * 4);
  bf16* qb    = (bf16*)alloc(2048ull * 32 * 128 * 2);
  bf16* kbuf  = (bf16*)alloc(2048ull * 8 * 128 * 2);
  bf16* vtb   = (bf16*)alloc(8ull * 128 * 2048 * 2);
  bf16* attnb = (bf16*)alloc(2048ull * 4096 * 2);
  float* tf   = (float*)alloc(1280ull * 256 * 4);
  bf16* tb    = (bf16*)alloc(1280ull * 256 * 2);
  float* t_im_f  = tf;               float* t_mem_f  = tf + 512 * 256;
  float* t2_im_f = tf + 640 * 256;   float* t2_mem_f = tf + 1152 * 256;
  bf16* t_im_b   = tb;               bf16* t_mem_b   = tb + 512 * 256;
  bf16* t2_im_b  = tb + 640 * 256;   bf16* t2_mem_b  = tb + 1152 * 256;
  (void)t_mem_f; (void)t2_mem_f;

  float* outp   = (float*)d_out;
  float* kc_out = outp + 2048ull * 4096;
  float* vc_out = kc_out + 4ull * 64 * 8 * 128;

  auto cvt = [&](const float* src, bf16* dst, size_t n) {
    size_t g = (n / 8 + 255) / 256;
    if (g > 2048) g = 2048;
    cvt_kernel<<<(unsigned)g, 256, 0, stream>>>(src, dst, (int)n);
  };
  cvt(hidden, xb, 2048ull * 4096);
  cvt(wqkv_w, wqkvb, 6144ull * 4096);
  cvt(wo_w, wob, 4096ull * 4096);
  cvt(wqkv_A, qAb, 256ull * 4096);
  cvt(wqkv_B, qBb, 6144ull * 256);
  cvt(wqkv_MA, qMAb, 256ull * 4096);
  cvt(wqkv_MB, qMBb, 6144ull * 256);
  cvt(wo_A, oAb, 256ull * 4096);
  cvt(wo_B, oBb, 4096ull * 256);
  cvt(wo_MA, oMAb, 256ull * 4096);
  cvt(wo_MB, oMBb, 4096ull * 256);
  zero_f32<<<1280, 256, 0, stream>>>(tf, 1280 * 256);

  // qkv = x @ wqkv^T (+ LoRA scatter-adds)
  gemm128<<<dim3(16, 48), 256, 0, stream>>>(xb, wqkvb, qkv, 2048, 6144, 4096);
  gemm64<1, 2><<<dim3(8, 4, 8), 256, 0, stream>>>(xb, qAb, im_idx, nullptr, nullptr, t_im_f, 512, 256, 4096, 256, 1.f);
  gemm64<1, 2><<<dim3(2, 4, 8), 256, 0, stream>>>(xb, qMAb, mem_idx, nullptr, nullptr, t_mem_f, 128, 256, 4096, 256, 1.f);
  cvt(tf, tb, 640 * 256);
  gemm64<0, 1><<<dim3(8, 96), 256, 0, stream>>>(t_im_b, qBb, nullptr, im_idx, nullptr, qkv, 512, 6144, 256, 6144, 1.f);
  gemm64<0, 1><<<dim3(2, 96), 256, 0, stream>>>(t_mem_b, qMBb, nullptr, mem_idx, nullptr, qkv, 128, 6144, 256, 6144, 1.f);

  // rope / extract / cache
  rope_q<<<16384, 256, 0, stream>>>(qkv, cosp, sinp, qb);
  rope_k<<<4096, 256, 0, stream>>>(qkv, cosp, sinp, kbuf);
  v_trans<<<dim3(32, 8), 256, 0, stream>>>(qkv, vtb);
  cache_copy<<<1024, 256, 0, stream>>>(kc_in, vc_in, kc_out, vc_out);
  cache_fill<<<128, 256, 0, stream>>>(qkv, mem_idx, blk_off, bcos, bsin, kc_out, vc_out);

  // attention
  flash<<<dim3(8, 32), 512, 0, stream>>>(qb, kbuf, vtb, attnb);

  // out = attn @ wo^T (+ LoRA scatter-adds)
  gemm128<<<dim3(16, 32), 256, 0, stream>>>(attnb, wob, outp, 2048, 4096, 4096);
  gemm64<1, 2><<<dim3(8, 4, 8), 256, 0, stream>>>(attnb, oAb, im_idx, nullptr, nullptr, t2_im_f, 512, 256, 4096, 256, 1.f);
  gemm64<1, 2><<<dim3(2, 4, 8), 256, 0, stream>>>(attnb, oMAb, mem_idx, nullptr, nullptr, t2_mem_f, 128, 256, 4096, 256, 1.f);
  cvt(t2_im_f, t2_im_b, 640 * 256);
  gemm64<0, 1><<<dim3(8, 64), 256, 0, stream>>>(t2_im_b, oBb, nullptr, im_idx, nullptr, outp, 512, 4096, 256, 4096, 1.f);
  gemm64<0, 1><<<dim3(2, 64), 256, 0, stream>>>(t2_mem_b, oMBb, nullptr, mem_idx, nullptr, outp, 128, 4096, 256, 4096, 1.f);
}